// Round 8
// baseline (709.881 us; speedup 1.0000x reference)
//
#include <hip/hip_runtime.h>

typedef unsigned short u16;

// ---------------------------------------------------------------------------
// Cross-kernel intermediates in module .bss (load-time allocated, not poisoned
// by the harness, graph-capture safe). ~2.26 MB.
// ---------------------------------------------------------------------------
__device__ float g_maxout[4 * 32 * 4096];   // 2 MB
__device__ float g_q[16384];
__device__ float g_qmean[16384];
__device__ float g_lit[128];
__device__ float g_sigfac[16384];

__global__ void zero_lit_kernel() {
    if (threadIdx.x < 128) g_lit[threadIdx.x] = 0.f;
}

// ---------------------------------------------------------------------------
// maxout[b][o][p] = sum_c KSA_w[o][c]*deep[b][c][p] + KSA_b[o]   (fp32 exact)
// ---------------------------------------------------------------------------
__global__ __launch_bounds__(256) void conv_deep_scalar(
    const float* __restrict__ W, const float* __restrict__ Bias,
    const float* __restrict__ X)
{
    const int idx = blockIdx.x * 256 + threadIdx.x;   // [0, 4*8*4096)
    const int p = idx & 4095;
    const int og = (idx >> 12) & 7;
    const int b = idx >> 15;
    const float* xp = X + (((long long)b * 512) << 12) + p;
    const float* wp = W + og * 4 * 512;
    float acc[4] = {0.f, 0.f, 0.f, 0.f};
    for (int c = 0; c < 512; ++c) {
        const float x = xp[(long long)c << 12];
#pragma unroll
        for (int k = 0; k < 4; ++k) acc[k] += wp[k * 512 + c] * x;
    }
#pragma unroll
    for (int k = 0; k < 4; ++k) {
        const int o = og * 4 + k;
        g_maxout[((b * 32 + o) << 12) + p] = acc[k] + Bias[o];
    }
}

// q[b][p] = max_j maxout[b][j][p]; qmean[b][p] = mean_j maxout[b][j][p]
__global__ __launch_bounds__(256) void qstats_kernel()
{
    const int idx = blockIdx.x * 256 + threadIdx.x;  // 16384
    const int b = idx >> 12;
    const int p = idx & 4095;
    const float* mp = g_maxout + (b << 17) + p;
    float mx = -3.4e38f, s = 0.f;
#pragma unroll
    for (int j = 0; j < 32; j++) {
        const float v = mp[j << 12];
        mx = fmaxf(mx, v);
        s += v;
    }
    g_q[idx] = mx;
    g_qmean[idx] = s * (1.f / 32.f);
}

// lit[b][l] = (1/hw) * sum_i q[b][i] * flat[b][i*32+l]   (C-order flat view)
// WITH /hw, faithful to the reference jax. (Round 7 falsified no-div: its
// 0.277 error == 0.5*att_max exactly == step-sig vs smooth-sig difference.)
__global__ __launch_bounds__(256) void lit_kernel()
{
    const int b = blockIdx.y;
    const int f0 = blockIdx.x * 8192;
    const int t = threadIdx.x;
    const float* mo = g_maxout + (b << 17);
    const float* qb = g_q + (b << 12);
    float acc = 0.f;
#pragma unroll
    for (int it = 0; it < 32; it++) {
        const int f = f0 + it * 256 + t;    // l = f&31 = t&31 (invariant)
        acc += qb[f >> 5] * mo[f];
    }
    __shared__ float red[256];
    red[t] = acc;
    __syncthreads();
    if (t < 32) {
        float s = 0.f;
#pragma unroll
        for (int k = 0; k < 8; k++) s += red[t + k * 32];
        atomicAdd(&g_lit[b * 32 + t], s * (1.f / 4096.f));
    }
}

// re_score[b][p] = sum_j lit[b][j]*maxout[b][j][p]   (fp32 -> output tail)
// sigfac = 1 + sigmoid(re_score)
__global__ __launch_bounds__(256) void rescore_kernel(float* __restrict__ out_re)
{
    const int idx = blockIdx.x * 256 + threadIdx.x;  // 16384
    const int b = idx >> 12;
    const int p = idx & 4095;
    const float* mo = g_maxout + (b << 17) + p;
    const float* lb = g_lit + b * 32;
    float r = 0.f;
#pragma unroll
    for (int j = 0; j < 32; j++) r += lb[j] * mo[j << 12];
    out_re[idx] = r;
    g_sigfac[idx] = 1.f + 1.f / (1.f + __expf(-r));
}

// ---------------------------------------------------------------------------
// att branch, scalar fp32, Kx recomputed per window element (never stored).
// Thread handles 8 consecutive channels at one output pixel p. FLOAT32 out.
// Zero-pad: unfold pads the POST-BIAS conv output with exact 0.
// ---------------------------------------------------------------------------
__global__ __launch_bounds__(256) void att_scalar(
    const float* __restrict__ W, const float* __restrict__ Bias,
    const float* __restrict__ X, float* __restrict__ out)
{
    const int idx = blockIdx.x * 256 + threadIdx.x;   // [0, 4*32*4096)
    const int p = idx & 4095;
    const int og = (idx >> 12) & 31;
    const int b = idx >> 17;
    const int ph = p >> 6, pw = p & 63;
    const int y0 = 2 * ph - 1, x0 = 2 * pw - 1;

    int off[9];
    bool ok[9];
#pragma unroll
    for (int ki = 0; ki < 3; ++ki)
#pragma unroll
        for (int kj = 0; kj < 3; ++kj) {
            const int y = y0 + ki, x = x0 + kj;
            const bool v = (y >= 0) & (y < 128) & (x >= 0) & (x < 128);
            ok[ki * 3 + kj] = v;
            off[ki * 3 + kj] = v ? ((y << 7) + x) : 0;   // clamp, mask later
        }

    const float* xb = X + ((long long)b << 22);
    const float* wp = W + (og << 11);        // 8 rows of 256
    float acc[8][9];
#pragma unroll
    for (int k = 0; k < 8; ++k)
#pragma unroll
        for (int j = 0; j < 9; ++j) acc[k][j] = 0.f;

    for (int c = 0; c < 256; ++c) {
        float xv[9];
#pragma unroll
        for (int j = 0; j < 9; ++j) xv[j] = xb[(c << 14) + off[j]];
#pragma unroll
        for (int k = 0; k < 8; ++k) {
            const float w = wp[(k << 8) + c];
#pragma unroll
            for (int j = 0; j < 9; ++j) acc[k][j] += w * xv[j];
        }
    }

    const float m = g_qmean[(b << 12) + p];
    const float sf = g_sigfac[(b << 12) + p];
#pragma unroll
    for (int k = 0; k < 8; ++k) {
        const int o = og * 8 + k;
        const float bias = Bias[o];
        float v[9];
#pragma unroll
        for (int j = 0; j < 9; ++j) v[j] = ok[j] ? (acc[k][j] + bias) : 0.f;
        float mx = -3.4e38f;
#pragma unroll
        for (int j = 0; j < 9; ++j) mx = fmaxf(mx, m * v[j]);
        float s = 0.f, a = 0.f;
#pragma unroll
        for (int j = 0; j < 9; ++j) {
            const float e = __expf(m * v[j] - mx);
            s += e;
            a += e * v[j];
        }
        out[(((long long)b * 256 + o) << 12) + p] = (a / s) * sf;
    }
}

extern "C" void kernel_launch(void* const* d_in, const int* in_sizes, int n_in,
                              void* d_out, int out_size, void* d_ws, size_t ws_size,
                              hipStream_t stream) {
    // Identify inputs by unique element count (robust to ordering).
    const float *shallow = 0, *deep = 0, *K_w = 0, *K_b = 0, *KSA_w = 0, *KSA_b = 0;
    for (int i = 0; i < n_in; ++i) {
        switch (in_sizes[i]) {
            case 16777216: shallow = (const float*)d_in[i]; break; // [4][256][128][128]
            case 8388608:  deep    = (const float*)d_in[i]; break; // [4][512][64][64]
            case 65536:    K_w     = (const float*)d_in[i]; break; // [256][256]
            case 256:      K_b     = (const float*)d_in[i]; break; // [256]
            case 16384:    KSA_w   = (const float*)d_in[i]; break; // [32][512]
            case 32:       KSA_b   = (const float*)d_in[i]; break; // [32]
        }
    }
    float* out = (float*)d_out;   // FP32: 4194304 att + 16384 re_score

    // 0) zero the lit accumulator every launch
    zero_lit_kernel<<<1, 128, 0, stream>>>();
    // 1) deep branch conv (fp32 exact)
    conv_deep_scalar<<<512, 256, 0, stream>>>(KSA_w, KSA_b, deep);
    // 2) per-pixel channel max/mean
    qstats_kernel<<<64, 256, 0, stream>>>();
    // 3) lit (channel-scrambled, WITH /hw per the reference)
    lit_kernel<<<dim3(16, 4), 256, 0, stream>>>();
    // 4) re_score (fp32 -> out tail) + sigmoid factor
    rescore_kernel<<<64, 256, 0, stream>>>(out + 4194304);
    // 5) att branch, scalar fp32, fused conv+unfold+softmax
    att_scalar<<<2048, 256, 0, stream>>>(K_w, K_b, shallow, out);
}

// Round 9
// 494.100 us; speedup vs baseline: 1.4367x; 1.4367x over previous
//
#include <hip/hip_runtime.h>

typedef unsigned short u16;
typedef __attribute__((ext_vector_type(8))) short short8;
typedef __attribute__((ext_vector_type(4))) float float4v;
typedef __attribute__((ext_vector_type(4))) unsigned short ushort4v;

__device__ __forceinline__ u16 f2bf(float f) {
    unsigned u = __float_as_uint(f);
    u += 0x7FFFu + ((u >> 16) & 1u);   // RNE
    return (u16)(u >> 16);
}
__device__ __forceinline__ float bf2f(u16 u) {
    return __uint_as_float(((unsigned)u) << 16);
}

// ---------------------------------------------------------------------------
// Module .bss intermediates (d_ws proved unreliable in rounds 3-6).
// ---------------------------------------------------------------------------
__device__ float g_maxout[4 * 32 * 4096];   // 2 MB fp32
__device__ float g_q[16384];
__device__ float g_qmean[16384];
__device__ float g_lit[128];
__device__ float g_sigfac[16384];
__device__ u16   g_Kw_bf[65536];            // K_w  bf16 (32 KB, L1-resident)
__device__ u16   g_KSAw_bf[16384];          // KSA_w bf16

// Zero lit + convert both weight matrices to bf16. Grid 320x256.
__global__ __launch_bounds__(256) void prep_kernel(
    const float* __restrict__ Kw, const float* __restrict__ KSAw)
{
    const int idx = blockIdx.x * 256 + threadIdx.x;
    if (idx < 128) g_lit[idx] = 0.f;
    if (idx < 65536) g_Kw_bf[idx] = f2bf(Kw[idx]);
    if (idx < 16384) g_KSAw_bf[idx] = f2bf(KSAw[idx]);
}

// ---------------------------------------------------------------------------
// Deep conv via MFMA: maxout[b][o][p] = sum_c KSA_w[o][c]*deep[b][c][p]+bias
// M=32, K=512, N=4096. W bf16 from .bss; deep fp32 cvt inline. fp32 out.
// ---------------------------------------------------------------------------
__global__ __launch_bounds__(256) void gemm_deep(
    const float* __restrict__ Bias, const float* __restrict__ X)
{
    const int t = threadIdx.x;
    const int wave = t >> 6, lane = t & 63;
    const int quad = lane >> 4, n16 = lane & 15;
    const int b = blockIdx.y;
    const int p = blockIdx.x * 64 + wave * 16 + n16;
    const float* Xb = X + ((long long)b << 21);

    float4v acc[2];
#pragma unroll
    for (int i = 0; i < 2; i++) acc[i] = (float4v){0.f, 0.f, 0.f, 0.f};

    for (int kb = 0; kb < 16; kb++) {
        const int kbase = (kb << 5) + (quad << 3);
        short8 bfrag;
        const float* xp = Xb + (kbase << 12) + p;
#pragma unroll
        for (int j = 0; j < 8; j++) bfrag[j] = (short)f2bf(xp[j << 12]);
#pragma unroll
        for (int ot = 0; ot < 2; ot++) {
            const short8 afrag = *(const short8*)(g_KSAw_bf + ((ot * 16 + n16) << 9) + kbase);
            acc[ot] = __builtin_amdgcn_mfma_f32_16x16x32_bf16(afrag, bfrag, acc[ot], 0, 0, 0);
        }
    }
#pragma unroll
    for (int ot = 0; ot < 2; ot++) {
#pragma unroll
        for (int r = 0; r < 4; r++) {
            const int o = ot * 16 + quad * 4 + r;
            g_maxout[((b * 32 + o) << 12) + p] = acc[ot][r] + Bias[o];
        }
    }
}

// q = channel max, qmean = channel mean
__global__ __launch_bounds__(256) void qstats_kernel()
{
    const int idx = blockIdx.x * 256 + threadIdx.x;  // 16384
    const int b = idx >> 12, p = idx & 4095;
    const float* mp = g_maxout + (b << 17) + p;
    float mx = -3.4e38f, s = 0.f;
#pragma unroll
    for (int j = 0; j < 32; j++) {
        const float v = mp[j << 12];
        mx = fmaxf(mx, v);
        s += v;
    }
    g_q[idx] = mx;
    g_qmean[idx] = s * (1.f / 32.f);
}

// lit[b][l] = (1/4096) * sum_i q[b][i] * flat[b][i*32+l]
__global__ __launch_bounds__(256) void lit_kernel()
{
    const int b = blockIdx.y;
    const int f0 = blockIdx.x * 8192;
    const int t = threadIdx.x;
    const float* mo = g_maxout + (b << 17);
    const float* qb = g_q + (b << 12);
    float acc = 0.f;
#pragma unroll
    for (int it = 0; it < 32; it++) {
        const int f = f0 + it * 256 + t;
        acc += qb[f >> 5] * mo[f];
    }
    __shared__ float red[256];
    red[t] = acc;
    __syncthreads();
    if (t < 32) {
        float s = 0.f;
#pragma unroll
        for (int k = 0; k < 8; k++) s += red[t + k * 32];
        atomicAdd(&g_lit[b * 32 + t], s * (1.f / 4096.f));
    }
}

// re_score -> out tail (fp32); sigfac = 1 + sigmoid(re)
__global__ __launch_bounds__(256) void rescore_kernel(float* __restrict__ out_re)
{
    const int idx = blockIdx.x * 256 + threadIdx.x;  // 16384
    const int b = idx >> 12, p = idx & 4095;
    const float* mo = g_maxout + (b << 17) + p;
    const float* lb = g_lit + b * 32;
    float r = 0.f;
#pragma unroll
    for (int j = 0; j < 32; j++) r += lb[j] * mo[j << 12];
    out_re[idx] = r;
    g_sigfac[idx] = 1.f + 1.f / (1.f + __expf(-r));
}

// ---------------------------------------------------------------------------
// Fused shallow branch (MFMA): Kx tile for a 3x33 input patch x 256 channels
// into LDS, then unfold(3,2,1)+softmax+att+sig for 1 output row x 16 cols.
// Kx never touches global memory. Block 256 thr; wave w owns o in [64w,64w+64).
// ---------------------------------------------------------------------------
#define KXS 264
__global__ __launch_bounds__(256) void kx_att_fused(
    const float* __restrict__ Bias, const float* __restrict__ X,
    float* __restrict__ out)
{
    __shared__ u16 kx[112 * KXS];   // 59136 B
    const int t = threadIdx.x;
    const int wave = t >> 6, lane = t & 63;
    const int quad = lane >> 4, n16 = lane & 15;
    const int b = blockIdx.y;
    const int orow = blockIdx.x >> 2;        // 0..63
    const int c0 = (blockIdx.x & 3) << 4;    // 0,16,32,48
    const int ybase = 2 * orow - 1;
    const int xbase = 2 * c0 - 1;
    const float* Xb = X + ((long long)b << 22);
    const int otb = wave << 6;

    for (int pt = 0; pt < 7; ++pt) {
        const int local = (pt << 4) + n16;   // 0..111 (99 real)
        const int ry = local / 33;
        const int rx = local - ry * 33;
        const int y = ybase + ry;
        const int x = xbase + rx;
        const bool img = (local < 99) & (y >= 0) & (y < 128) & (x >= 0) & (x < 128);
        const int sp = img ? ((y << 7) + x) : 0;   // clamped: no OOB

        float4v acc[4];
#pragma unroll
        for (int i = 0; i < 4; ++i) acc[i] = (float4v){0.f, 0.f, 0.f, 0.f};

        for (int kb = 0; kb < 8; ++kb) {
            const int kbase = (kb << 5) + (quad << 3);
            short8 bfrag;
#pragma unroll
            for (int j = 0; j < 8; ++j)
                bfrag[j] = img ? (short)f2bf(Xb[sp + ((kbase + j) << 14)]) : (short)0;
#pragma unroll
            for (int i = 0; i < 4; ++i) {
                const short8 afrag = *(const short8*)(g_Kw_bf + ((otb + (i << 4) + n16) << 8) + kbase);
                acc[i] = __builtin_amdgcn_mfma_f32_16x16x32_bf16(afrag, bfrag, acc[i], 0, 0, 0);
            }
        }
        // C/D: row(o)=quad*4+r, col(patch)=local (this lane's col). Zero-pad
        // out-of-image: unfold pads the POST-BIAS conv output with exact 0.
#pragma unroll
        for (int i = 0; i < 4; ++i) {
            const int o4 = otb + (i << 4) + (quad << 2);
            ushort4v pack;
#pragma unroll
            for (int r = 0; r < 4; ++r)
                pack[r] = img ? f2bf(acc[i][r] + Bias[o4 + r]) : (u16)0;
            *(ushort4v*)&kx[local * KXS + o4] = pack;
        }
    }
    __syncthreads();

    // Phase 2: thread t owns channel o=t for 16 output cols.
    const int o = t;
    const float* qmb = g_qmean + (b << 12) + (orow << 6) + c0;
    const float* sfb = g_sigfac + (b << 12) + (orow << 6) + c0;
    float res[16];
#pragma unroll
    for (int jj = 0; jj < 16; ++jj) {
        const float m = qmb[jj];
        float v[9];
#pragma unroll
        for (int ki = 0; ki < 3; ++ki)
#pragma unroll
            for (int kj = 0; kj < 3; ++kj)
                v[ki * 3 + kj] = bf2f(kx[(ki * 33 + 2 * jj + kj) * KXS + o]);
        float mx = -3.4e38f;
#pragma unroll
        for (int k = 0; k < 9; ++k) mx = fmaxf(mx, m * v[k]);
        float s = 0.f, a = 0.f;
#pragma unroll
        for (int k = 0; k < 9; ++k) {
            const float e = __expf(m * v[k] - mx);
            s += e;
            a += e * v[k];
        }
        res[jj] = (a / s) * sfb[jj];
    }
    float* op = out + (((long long)(b << 8) + o) << 12) + (orow << 6) + c0;
#pragma unroll
    for (int g = 0; g < 4; ++g)
        *(float4v*)(op + 4 * g) = (float4v){res[4*g], res[4*g+1], res[4*g+2], res[4*g+3]};
}

extern "C" void kernel_launch(void* const* d_in, const int* in_sizes, int n_in,
                              void* d_out, int out_size, void* d_ws, size_t ws_size,
                              hipStream_t stream) {
    const float *shallow = 0, *deep = 0, *K_w = 0, *K_b = 0, *KSA_w = 0, *KSA_b = 0;
    for (int i = 0; i < n_in; ++i) {
        switch (in_sizes[i]) {
            case 16777216: shallow = (const float*)d_in[i]; break;
            case 8388608:  deep    = (const float*)d_in[i]; break;
            case 65536:    K_w     = (const float*)d_in[i]; break;
            case 256:      K_b     = (const float*)d_in[i]; break;
            case 16384:    KSA_w   = (const float*)d_in[i]; break;
            case 32:       KSA_b   = (const float*)d_in[i]; break;
        }
    }
    float* out = (float*)d_out;   // FP32: 4194304 att + 16384 re_score

    // 0) zero lit + bf16-convert weight matrices
    prep_kernel<<<320, 256, 0, stream>>>(K_w, KSA_w);
    // 1) deep conv (MFMA)
    gemm_deep<<<dim3(64, 4), 256, 0, stream>>>(KSA_b, deep);
    // 2) per-pixel channel max/mean
    qstats_kernel<<<64, 256, 0, stream>>>();
    // 3) lit (channel-scrambled, /hw)
    lit_kernel<<<dim3(16, 4), 256, 0, stream>>>();
    // 4) re_score (fp32 -> out tail) + sigmoid factor
    rescore_kernel<<<64, 256, 0, stream>>>(out + 4194304);
    // 5) fused shallow conv (MFMA) + windowed softmax attention + scaling
    kx_att_fused<<<dim3(256, 4), 256, 0, stream>>>(K_b, shallow, out);
}

// Round 10
// 244.459 us; speedup vs baseline: 2.9039x; 2.0212x over previous
//
#include <hip/hip_runtime.h>

typedef unsigned short u16;
typedef __attribute__((ext_vector_type(8))) short short8;
typedef __attribute__((ext_vector_type(4))) float float4v;

__device__ __forceinline__ u16 f2bf(float f) {
    unsigned u = __float_as_uint(f);
    u += 0x7FFFu + ((u >> 16) & 1u);   // RNE
    return (u16)(u >> 16);
}
__device__ __forceinline__ float bf2f(u16 u) {
    return __uint_as_float(((unsigned)u) << 16);
}

// ---------------------------------------------------------------------------
// Module .bss intermediates (d_ws proved unreliable in rounds 3-6).
// ---------------------------------------------------------------------------
__device__ float g_maxout[4 * 32 * 4096];   // 2 MB fp32
__device__ float g_q[16384];
__device__ float g_qmean[16384];
__device__ float g_lit[128];
__device__ float g_sigfac[16384];
__device__ u16   g_Kw_bf[65536];            // K_w  bf16 (L1/L2-resident)
__device__ u16   g_KSAw_bf[16384];          // KSA_w bf16
__device__ u16   g_Kx[4 * 256 * 16384];     // Kx bf16, 33.5 MB

// Zero lit + convert both weight matrices to bf16.
__global__ __launch_bounds__(256) void prep_kernel(
    const float* __restrict__ Kw, const float* __restrict__ KSAw)
{
    const int idx = blockIdx.x * 256 + threadIdx.x;
    if (idx < 128) g_lit[idx] = 0.f;
    if (idx < 65536) g_Kw_bf[idx] = f2bf(Kw[idx]);
    if (idx < 16384) g_KSAw_bf[idx] = f2bf(KSAw[idx]);
}

// ---------------------------------------------------------------------------
// Deep conv via MFMA: maxout[b][o][p] = sum_c KSA_w[o][c]*deep[b][c][p]+bias
// M=32, K=512, N=4096 per batch. fp32 out to .bss.
// ---------------------------------------------------------------------------
__global__ __launch_bounds__(256) void gemm_deep(
    const float* __restrict__ Bias, const float* __restrict__ X)
{
    const int t = threadIdx.x;
    const int wave = t >> 6, lane = t & 63;
    const int quad = lane >> 4, n16 = lane & 15;
    const int b = blockIdx.y;
    const int p = blockIdx.x * 64 + wave * 16 + n16;
    const float* Xb = X + ((long long)b << 21);

    float4v acc[2];
#pragma unroll
    for (int i = 0; i < 2; i++) acc[i] = (float4v){0.f, 0.f, 0.f, 0.f};

    for (int kb = 0; kb < 16; kb++) {
        const int kbase = (kb << 5) + (quad << 3);
        short8 bfrag;
        const float* xp = Xb + (kbase << 12) + p;
#pragma unroll
        for (int j = 0; j < 8; j++) bfrag[j] = (short)f2bf(xp[j << 12]);
#pragma unroll
        for (int ot = 0; ot < 2; ot++) {
            const short8 afrag = *(const short8*)(g_KSAw_bf + ((ot * 16 + n16) << 9) + kbase);
            acc[ot] = __builtin_amdgcn_mfma_f32_16x16x32_bf16(afrag, bfrag, acc[ot], 0, 0, 0);
        }
    }
#pragma unroll
    for (int ot = 0; ot < 2; ot++) {
#pragma unroll
        for (int r = 0; r < 4; r++) {
            const int o = ot * 16 + quad * 4 + r;
            g_maxout[((b * 32 + o) << 12) + p] = acc[ot][r] + Bias[o];
        }
    }
}

// q = channel max, qmean = channel mean
__global__ __launch_bounds__(256) void qstats_kernel()
{
    const int idx = blockIdx.x * 256 + threadIdx.x;  // 16384
    const int b = idx >> 12, p = idx & 4095;
    const float* mp = g_maxout + (b << 17) + p;
    float mx = -3.4e38f, s = 0.f;
#pragma unroll
    for (int j = 0; j < 32; j++) {
        const float v = mp[j << 12];
        mx = fmaxf(mx, v);
        s += v;
    }
    g_q[idx] = mx;
    g_qmean[idx] = s * (1.f / 32.f);
}

// lit[b][l] = (1/4096) * sum_i q[b][i] * flat[b][i*32+l]
__global__ __launch_bounds__(256) void lit_kernel()
{
    const int b = blockIdx.y;
    const int f0 = blockIdx.x * 8192;
    const int t = threadIdx.x;
    const float* mo = g_maxout + (b << 17);
    const float* qb = g_q + (b << 12);
    float acc = 0.f;
#pragma unroll
    for (int it = 0; it < 32; it++) {
        const int f = f0 + it * 256 + t;
        acc += qb[f >> 5] * mo[f];
    }
    __shared__ float red[256];
    red[t] = acc;
    __syncthreads();
    if (t < 32) {
        float s = 0.f;
#pragma unroll
        for (int k = 0; k < 8; k++) s += red[t + k * 32];
        atomicAdd(&g_lit[b * 32 + t], s * (1.f / 4096.f));
    }
}

// re_score -> out tail (fp32); sigfac = 1 + sigmoid(re)
__global__ __launch_bounds__(256) void rescore_kernel(float* __restrict__ out_re)
{
    const int idx = blockIdx.x * 256 + threadIdx.x;  // 16384
    const int b = idx >> 12, p = idx & 4095;
    const float* mo = g_maxout + (b << 17) + p;
    const float* lb = g_lit + b * 32;
    float r = 0.f;
#pragma unroll
    for (int j = 0; j < 32; j++) r += lb[j] * mo[j << 12];
    out_re[idx] = r;
    g_sigfac[idx] = 1.f + 1.f / (1.f + __expf(-r));
}

// ---------------------------------------------------------------------------
// Shallow conv as a fat GEMM: Kx[b][o][s] = sum_c K_w[o][c]*shallow[b][c][s]
// + bias, stored bf16 to .bss. M=256 (16 o-tiles per wave => 16 MFMA per
// 8-load staging), N=16384/batch, K=256. Wave w owns cols [blk*64+16w, +16).
// ---------------------------------------------------------------------------
__global__ __launch_bounds__(256) void gemm_kx(
    const float* __restrict__ Bias, const float* __restrict__ X)
{
    const int t = threadIdx.x;
    const int wave = t >> 6, lane = t & 63;
    const int quad = lane >> 4, n16 = lane & 15;
    const int b = blockIdx.y;
    const int p = blockIdx.x * 64 + wave * 16 + n16;     // spatial 0..16383
    const float* Xb = X + ((long long)b << 22);

    float4v acc[16];
#pragma unroll
    for (int i = 0; i < 16; i++) acc[i] = (float4v){0.f, 0.f, 0.f, 0.f};

    for (int kb = 0; kb < 8; kb++) {
        const int kbase = (kb << 5) + (quad << 3);
        short8 bfrag;
        const float* xp = Xb + (kbase << 14) + p;
#pragma unroll
        for (int j = 0; j < 8; j++) bfrag[j] = (short)f2bf(xp[j << 14]);
#pragma unroll
        for (int ot = 0; ot < 16; ot++) {
            const short8 afrag = *(const short8*)(g_Kw_bf + ((ot * 16 + n16) << 8) + kbase);
            acc[ot] = __builtin_amdgcn_mfma_f32_16x16x32_bf16(afrag, bfrag, acc[ot], 0, 0, 0);
        }
    }
    // C/D: col(p)=n16 (this lane's p), row(o)=ot*16+quad*4+r
    u16* kxb = g_Kx + (((long long)b << 8) << 14);
#pragma unroll
    for (int ot = 0; ot < 16; ot++) {
#pragma unroll
        for (int r = 0; r < 4; r++) {
            const int o = ot * 16 + quad * 4 + r;
            kxb[(o << 14) + p] = f2bf(acc[ot][r] + Bias[o]);
        }
    }
}

// ---------------------------------------------------------------------------
// Windowed softmax attention from bf16 Kx. One thread per (b,o,p_out).
// Coalesced: 256 consecutive p per block; out write fp32 coalesced.
// ---------------------------------------------------------------------------
__global__ __launch_bounds__(256) void att_window(float* __restrict__ out)
{
    const int p = blockIdx.x * 256 + threadIdx.x;   // 0..4095
    const int o = blockIdx.y;
    const int b = blockIdx.z;
    const int ph = p >> 6, pw = p & 63;
    const int y0 = 2 * ph - 1, x0 = 2 * pw - 1;
    const u16* kxp = g_Kx + ((((long long)b << 8) + o) << 14);

    float v[9];
#pragma unroll
    for (int ki = 0; ki < 3; ++ki) {
        const int y = y0 + ki;
        const bool yok = (y >= 0) & (y < 128);
#pragma unroll
        for (int kj = 0; kj < 3; ++kj) {
            const int x = x0 + kj;
            const bool okk = yok & (x >= 0) & (x < 128);
            v[ki * 3 + kj] = okk ? bf2f(kxp[(y << 7) + x]) : 0.f;
        }
    }
    const float m = g_qmean[(b << 12) + p];
    const float sf = g_sigfac[(b << 12) + p];
    float mx = -3.4e38f;
#pragma unroll
    for (int k = 0; k < 9; ++k) mx = fmaxf(mx, m * v[k]);
    float s = 0.f, a = 0.f;
#pragma unroll
    for (int k = 0; k < 9; ++k) {
        const float e = __expf(m * v[k] - mx);
        s += e;
        a += e * v[k];
    }
    out[((((long long)b << 8) + o) << 12) + p] = (a / s) * sf;
}

extern "C" void kernel_launch(void* const* d_in, const int* in_sizes, int n_in,
                              void* d_out, int out_size, void* d_ws, size_t ws_size,
                              hipStream_t stream) {
    const float *shallow = 0, *deep = 0, *K_w = 0, *K_b = 0, *KSA_w = 0, *KSA_b = 0;
    for (int i = 0; i < n_in; ++i) {
        switch (in_sizes[i]) {
            case 16777216: shallow = (const float*)d_in[i]; break;
            case 8388608:  deep    = (const float*)d_in[i]; break;
            case 65536:    K_w     = (const float*)d_in[i]; break;
            case 256:      K_b     = (const float*)d_in[i]; break;
            case 16384:    KSA_w   = (const float*)d_in[i]; break;
            case 32:       KSA_b   = (const float*)d_in[i]; break;
        }
    }
    float* out = (float*)d_out;   // FP32: 4194304 att + 16384 re_score

    // 0) zero lit + bf16-convert weight matrices
    prep_kernel<<<320, 256, 0, stream>>>(K_w, KSA_w);
    // 1) deep conv (MFMA)
    gemm_deep<<<dim3(64, 4), 256, 0, stream>>>(KSA_b, deep);
    // 2) per-pixel channel max/mean
    qstats_kernel<<<64, 256, 0, stream>>>();
    // 3) lit (channel-scrambled, /hw)
    lit_kernel<<<dim3(16, 4), 256, 0, stream>>>();
    // 4) re_score (fp32 -> out tail) + sigmoid factor
    rescore_kernel<<<64, 256, 0, stream>>>(out + 4194304);
    // 5) shallow conv as fat GEMM -> Kx bf16 (.bss)
    gemm_kx<<<dim3(256, 4), 256, 0, stream>>>(K_b, shallow);
    // 6) windowed softmax attention + sig scaling
    att_window<<<dim3(16, 256, 4), 256, 0, stream>>>(out);
}